// Round 4
// baseline (458.352 us; speedup 1.0000x reference)
//
#include <hip/hip_runtime.h>
#include <hip/hip_bf16.h>
#include <math.h>

using bf16 = __hip_bfloat16;
typedef __attribute__((ext_vector_type(8))) short short8;
typedef __attribute__((ext_vector_type(4))) short s16x4;
typedef __attribute__((ext_vector_type(4))) float f32x4;

constexpr int S = 4096, D = 1024, H = 16, HD = 64, FF = 4096;

static __device__ __forceinline__ float tof(bf16 v) { return __bfloat162float(v); }
static __device__ __forceinline__ bf16 tob(float v) { return __float2bfloat16(v); }
static __device__ __forceinline__ short tobs(float v) {
    bf16 h = __float2bfloat16(v);
    return *reinterpret_cast<short*>(&h);
}
static __device__ __forceinline__ unsigned pkbf16(float a, float b) {
    __hip_bfloat162 h = __float22bfloat162_rn(make_float2(a, b));
    return *reinterpret_cast<unsigned*>(&h);
}

#if __has_builtin(__builtin_amdgcn_exp2f)
#define EXP2(x) __builtin_amdgcn_exp2f(x)
#else
#define EXP2(x) exp2f(x)
#endif

static __device__ __forceinline__ f32x4 mfma16(short8 a, short8 b, f32x4 c) {
    return __builtin_amdgcn_mfma_f32_16x16x32_bf16(a, b, c, 0, 0, 0);
}
// async global->LDS, 16B per lane; LDS dest = wave-uniform base + lane*16
static __device__ __forceinline__ void stage16(const bf16* g, bf16* l) {
    __builtin_amdgcn_global_load_lds((__attribute__((address_space(1))) void*)g,
                                     (__attribute__((address_space(3))) void*)l, 16, 0, 0);
}
// cross-lane quad redistribution primitives (gfx950)
static __device__ __forceinline__ void pl32swap(unsigned& a, unsigned& b) {
    asm("v_permlane32_swap_b32 %0, %1" : "+v"(a), "+v"(b));
}
static __device__ __forceinline__ void pl16swap(unsigned& a, unsigned& b) {
    asm("v_permlane16_swap_b32 %0, %1" : "+v"(a), "+v"(b));
}

// ---------------- LayerNorm: fp32 in -> bf16 out ----------------------------
__global__ __launch_bounds__(256) void ln_kernel(const float* __restrict__ x,
                                                 const float* __restrict__ scale,
                                                 const float* __restrict__ bias,
                                                 bf16* __restrict__ y) {
    int row = blockIdx.x, t = threadIdx.x;
    const float* xr = x + (size_t)row * D;
    float v[4], s = 0.f, ss = 0.f;
#pragma unroll
    for (int i = 0; i < 4; ++i) {
        v[i] = xr[t + 256 * i];
        s += v[i]; ss += v[i] * v[i];
    }
    __shared__ float r0[256], r1[256];
    r0[t] = s; r1[t] = ss;
    __syncthreads();
    for (int off = 128; off; off >>= 1) {
        if (t < off) { r0[t] += r0[t + off]; r1[t] += r1[t + off]; }
        __syncthreads();
    }
    float mu  = r0[0] * (1.f / D);
    float var = r1[0] * (1.f / D) - mu * mu;
    float inv = rsqrtf(var + 1e-6f);
    bf16* yr = y + (size_t)row * D;
#pragma unroll
    for (int i = 0; i < 4; ++i) {
        int c = t + 256 * i;
        yr[c] = tob((v[i] - mu) * inv * scale[c] + bias[c]);
    }
}

// ------- all weight transposes (fp32 KxN -> bf16 NxK) + bias concat, fused --
__global__ __launch_bounds__(256) void wtrans_all(
    const float* __restrict__ Wq, const float* __restrict__ Wk,
    const float* __restrict__ Wv, const float* __restrict__ Wo,
    const float* __restrict__ W1, const float* __restrict__ W2,
    const float* __restrict__ bq, const float* __restrict__ bk,
    const float* __restrict__ bv,
    bf16* __restrict__ BTqkv, bf16* __restrict__ BTo,
    bf16* __restrict__ BT1, bf16* __restrict__ BT2, float* __restrict__ bqkv) {
    int id = blockIdx.x;
    if (id >= 12288) {
        int i = (id - 12288) * 256 + threadIdx.x;  // 3072
        bqkv[i] = i < 1024 ? bq[i] : (i < 2048 ? bk[i - 1024] : bv[i - 2048]);
        return;
    }
    const float* W; bf16* dst; int K, N, local;
    if (id < 3072)      { int s = id >> 10; W = s == 0 ? Wq : (s == 1 ? Wk : Wv);
                          dst = BTqkv + (size_t)s * 1048576; K = 1024; N = 1024; local = id & 1023; }
    else if (id < 4096) { W = Wo; dst = BTo; K = 1024; N = 1024; local = id - 3072; }
    else if (id < 8192) { W = W1; dst = BT1; K = 1024; N = 4096; local = id - 4096; }
    else                { W = W2; dst = BT2; K = 4096; N = 1024; local = id - 8192; }
    int ls = (N == 4096) ? 7 : 5;                  // log2(N/32)
    int nt = (local & ((1 << ls) - 1)) << 5, kt = (local >> ls) << 5;
    __shared__ float t[32][33];
    int tid = threadIdx.x, r = tid >> 5, c = tid & 31;
#pragma unroll
    for (int p = 0; p < 4; ++p)
        t[r + p * 8][c] = W[(size_t)(kt + r + p * 8) * N + nt + c];
    __syncthreads();
#pragma unroll
    for (int p = 0; p < 4; ++p)
        dst[(size_t)(nt + r + p * 8) * K + kt + c] = tob(t[c][r + p * 8]);
}

// ============= 256x256 8-phase MFMA GEMM (T2+T3+T4+T5 template) =============
// BM=BN=256, BK=64, 8 waves (2M x 4N), 512 thr, LDS 128 KiB dbuf.
// Per K-tile: 4 phases, each {stage 1 half-tile; barrier; ds_read subtile;
// 16 MFMA (one quadrant x K=64)}. vmcnt(6) once per K-tile (3 halves in
// flight). LDS rows 128 B, full XOR swizzle chunk ^= row&7 applied on the
// pre-swizzled GLOBAL source (gload_lds dest linear, rule #21) and on reads.
#define EPI_QKV  3  // q/k: +bias, rope -> QK (stride 2048); v: -> VT transposed
#define EPI_GELU 2  // bf16 out = gelu(acc + bias)

template <int EPI>
__global__ __launch_bounds__(512, 2) void gemm256(
    const bf16* __restrict__ A, const bf16* __restrict__ BT,
    const float* __restrict__ bias, void* out, void* out2, int N, int K) {
    __shared__ bf16 lds[2][2][2][8192];  // [buf][A/B][half: 128 rows x 64 k]
    const int tid = threadIdx.x;
    const int w = tid >> 6, lane = tid & 63;
    const int quad = lane >> 4, l16 = lane & 15;
    const int wr = w >> 2, wn = w & 3;
    // XCD-bijective block swizzle (nwg % 8 == 0 for all call sites)
    const int gx = gridDim.x, nwg = gx * gridDim.y;
    int bid = blockIdx.y * gx + blockIdx.x;
    bid = (bid & 7) * (nwg >> 3) + (bid >> 3);
    const int rowBase = (bid / gx) * 256, colBase = (bid % gx) * 256;

    const int srow = lane >> 3;                       // staging row 0..7
    const int schunk8 = ((lane & 7) ^ srow) * 8;      // pre-swizzled src chunk
    const int cxor = l16 & 7;                         // read-side XOR key

    f32x4 acc[8][4] = {};

    // stage one 128x64 half (16 KB): 2 gload_lds per wave, 8 rows each
    auto stageHalf = [&](int b, int mat, int h, int tk) {
        const bf16* base = mat ? BT : A;
        const int rb = (mat ? colBase : rowBase) + h * 128;
#pragma unroll
        for (int i = 0; i < 2; ++i) {
            int r = (w * 2 + i) * 8 + srow;
            stage16(base + (size_t)(rb + r) * K + tk * 64 + schunk8,
                    &lds[b][mat][h][(w * 2 + i) * 512]);
        }
    };
    short8 a[4][2], b0[2][2], b1[2][2];
    auto ldA = [&](int b, int mh) {
#pragma unroll
        for (int mf = 0; mf < 4; ++mf)
#pragma unroll
            for (int s = 0; s < 2; ++s)
                a[mf][s] = *(const short8*)&lds[b][0][wr]
                    [(mh * 64 + mf * 16 + l16) * 64 + ((s * 4 + quad) ^ cxor) * 8];
    };
    auto ldB = [&](int b, int nh, short8 bb[2][2]) {
#pragma unroll
        for (int n2 = 0; n2 < 2; ++n2)
#pragma unroll
            for (int s = 0; s < 2; ++s)
                bb[n2][s] = *(const short8*)&lds[b][1][wn >> 1]
                    [((wn & 1) * 64 + (nh * 2 + n2) * 16 + l16) * 64 + ((s * 4 + quad) ^ cxor) * 8];
    };
    auto domm = [&](short8 bb[2][2], int mh, int nh) {
        __builtin_amdgcn_s_setprio(1);
#pragma unroll
        for (int mf = 0; mf < 4; ++mf)
#pragma unroll
            for (int n2 = 0; n2 < 2; ++n2)
#pragma unroll
                for (int s = 0; s < 2; ++s)
                    acc[mh * 4 + mf][nh * 2 + n2] =
                        mfma16(a[mf][s], bb[n2][s], acc[mh * 4 + mf][nh * 2 + n2]);
        __builtin_amdgcn_s_setprio(0);
    };

    const int nT = K >> 6;
    // prologue: B0(0) A0(0) B1(0) A1(0) B0(1) A0(1)  (order feeds vmcnt calc)
    stageHalf(0, 1, 0, 0); stageHalf(0, 0, 0, 0);
    stageHalf(0, 1, 1, 0); stageHalf(0, 0, 1, 0);
    if (nT > 1) { stageHalf(1, 1, 0, 1); stageHalf(1, 0, 0, 1); }

    for (int t = 0; t < nT; ++t) {
        const int b = t & 1, bn = b ^ 1;
        // ---- phase 1: stage B1(t+1); publish tile t; Q(0,0)
        asm volatile("" ::: "memory");
        if (t + 1 < nT) {
            stageHalf(bn, 1, 1, t + 1);
            asm volatile("s_waitcnt vmcnt(6)" ::: "memory");  // tile t landed
        } else {
            asm volatile("s_waitcnt vmcnt(0)" ::: "memory");
        }
        __builtin_amdgcn_s_barrier();
        ldA(b, 0); ldB(b, 0, b0);
        domm(b0, 0, 0);
        // ---- phase 2: stage A1(t+1); Q(0,1)
        asm volatile("" ::: "memory");
        if (t + 1 < nT) stageHalf(bn, 0, 1, t + 1);
        __builtin_amdgcn_s_barrier();
        ldB(b, 1, b1);
        domm(b1, 0, 1);
        // ---- phase 3: stage B0(t+2); Q(1,1)
        asm volatile("" ::: "memory");
        if (t + 2 < nT) stageHalf(b, 1, 0, t + 2);
        __builtin_amdgcn_s_barrier();
        ldA(b, 1);
        domm(b1, 1, 1);
        // ---- phase 4: stage A0(t+2); Q(1,0) (all operands in regs)
        asm volatile("" ::: "memory");
        if (t + 2 < nT) stageHalf(b, 0, 0, t + 2);
        __builtin_amdgcn_s_barrier();
        domm(b0, 1, 0);
    }

    if (EPI == EPI_QKV) {
        bf16* QKo = (bf16*)out;   // (S, 2048) roped q|k
        bf16* VTo = (bf16*)out2;  // (H*64, S)
        if (colBase >= 2048) {  // V section: write transposed VT[c-2048][s]
#pragma unroll
            for (int nf = 0; nf < 4; ++nf) {
                int c = colBase + wn * 64 + nf * 16 + l16;
                float bj = bias[c];
                size_t cc = (size_t)(c - 2048) * 4096;
#pragma unroll
                for (int mf = 0; mf < 8; ++mf) {
                    int r0 = rowBase + wr * 128 + mf * 16 + quad * 4;
                    s16x4 ov = {tobs(acc[mf][nf][0] + bj), tobs(acc[mf][nf][1] + bj),
                                tobs(acc[mf][nf][2] + bj), tobs(acc[mf][nf][3] + bj)};
                    *(s16x4*)(VTo + cc + r0) = ov;
                }
            }
        } else {  // Q or K: bias + rope (pairs are (nf, nf+2) in-register)
            const bool isq = colBase < 1024;
            const float qs = isq ? 0.125f * 1.44269504088896f : 1.f;
#pragma unroll
            for (int j2 = 0; j2 < 2; ++j2) {
                int dim = j2 * 16 + l16;
                float freq = __expf(-(float)dim * (9.210340371976184f / 32.f));
                int c1 = colBase + wn * 64 + j2 * 16 + l16, c2 = c1 + 32;
                float b1v = bias[c1], b2v = bias[c2];
#pragma unroll
                for (int mf = 0; mf < 8; ++mf) {
#pragma unroll
                    for (int reg = 0; reg < 4; ++reg) {
                        int sr2 = rowBase + wr * 128 + mf * 16 + quad * 4 + reg;
                        float sn, cs;
                        sincosf((float)sr2 * freq, &sn, &cs);
                        float x1 = acc[mf][j2][reg] + b1v;
                        float x2 = acc[mf][j2 + 2][reg] + b2v;
                        QKo[(size_t)sr2 * 2048 + c1] = tob((x1 * cs - x2 * sn) * qs);
                        QKo[(size_t)sr2 * 2048 + c2] = tob((x2 * cs + x1 * sn) * qs);
                    }
                }
            }
        }
    } else {  // EPI_GELU
#pragma unroll
        for (int nf = 0; nf < 4; ++nf) {
            int c = colBase + wn * 64 + nf * 16 + l16;
            float bj = bias[c];
#pragma unroll
            for (int mf = 0; mf < 8; ++mf) {
                int r0 = rowBase + wr * 128 + mf * 16 + quad * 4;
#pragma unroll
                for (int reg = 0; reg < 4; ++reg) {
                    float val = acc[mf][nf][reg] + bj;
                    float g = 0.5f * val * (1.f + erff(val * 0.70710678118f));
                    ((bf16*)out)[(size_t)(r0 + reg) * N + c] = tob(g);
                }
            }
        }
    }
}

// ---------------- legacy MFMA GEMM (2-phase dbuf + swizzle), MT=64 ----------
#define EPI_RES  1  // fp32 out = acc + bias + resid(fp32)   (out may alias resid)
#define EPI_PART 4  // fp32 out = acc (split-K partial, out += z*M*N)

template <int EPI, int MT>
__global__ __launch_bounds__(256, MT == 128 ? 2 : 3) void gemm_bt(
    const bf16* __restrict__ A, const bf16* __restrict__ BT,
    const float* __restrict__ bias, const float* resid, void* out, void* out2,
    int M, int N, int K, int kLen) {
    constexpr int NJ = (MT == 128) ? 4 : 2;
    __shared__ bf16 As[2][MT * 32];
    __shared__ bf16 Bs[2][128 * 32];
    const int tid = threadIdx.x;
    const int w = tid >> 6, lane = tid & 63;
    const int quad = lane >> 4, l16 = lane & 15;
    const int rowBase = blockIdx.y * MT, colBase = blockIdx.x * 128;
    const int kStart = blockIdx.z * kLen;
    const int wr = (MT == 128) ? (w >> 1) * 64 : 0;
    const int wc = (MT == 128) ? (w & 1) * 64 : w * 32;
    const int sr = lane >> 2;
    const int skb = (((lane & 3) ^ ((lane >> 3) & 3)) * 8);
    const int fr = (l16 >> 1) & 3;
    f32x4 acc[4][NJ] = {};

    auto stage = [&](int k0, int b) {
        if constexpr (MT == 128) {
#pragma unroll
            for (int t = 0; t < 2; ++t) {
                int inst = w * 2 + t;
                int r = inst * 16 + sr;
                stage16(A  + (size_t)(rowBase + r) * K + kStart + k0 + skb, &As[b][inst * 512]);
                stage16(BT + (size_t)(colBase + r) * K + kStart + k0 + skb, &Bs[b][inst * 512]);
            }
        } else {
            stage16(A + (size_t)(rowBase + w * 16 + sr) * K + kStart + k0 + skb, &As[b][w * 512]);
#pragma unroll
            for (int t = 0; t < 2; ++t) {
                int inst = w + t * 4;
                stage16(BT + (size_t)(colBase + inst * 16 + sr) * K + kStart + k0 + skb, &Bs[b][inst * 512]);
            }
        }
    };

    stage(0, 0);
    const int nSteps = kLen >> 5;
    for (int s = 0; s < nSteps; ++s) {
        const int cb = s & 1;
        __builtin_amdgcn_s_barrier();
        if (s + 1 < nSteps) {
            stage((s + 1) << 5, cb ^ 1);
            if constexpr (MT == 128) asm volatile("s_waitcnt vmcnt(4)" ::: "memory");
            else                     asm volatile("s_waitcnt vmcnt(3)" ::: "memory");
        } else {
            asm volatile("s_waitcnt vmcnt(0)" ::: "memory");
        }
        __builtin_amdgcn_s_barrier();
        const bf16* pa = &As[cb][(wr + l16) * 32 + (quad ^ fr) * 8];
        const bf16* pb = &Bs[cb][(wc + l16) * 32 + (quad ^ fr) * 8];
        short8 a[4], b[NJ];
#pragma unroll
        for (int i = 0; i < 4; ++i) a[i] = *(const short8*)(pa + i * 512);
#pragma unroll
        for (int j = 0; j < NJ; ++j) b[j] = *(const short8*)(pb + j * 512);
#pragma unroll
        for (int i = 0; i < 4; ++i)
#pragma unroll
            for (int j = 0; j < NJ; ++j) acc[i][j] = mfma16(a[i], b[j], acc[i][j]);
    }
#pragma unroll
    for (int j = 0; j < NJ; ++j) {
        int c = colBase + wc + j * 16 + l16;
        float bj = (EPI == EPI_PART) ? 0.f : bias[c];
#pragma unroll
        for (int i = 0; i < 4; ++i) {
            int r0 = rowBase + wr + i * 16 + quad * 4;
#pragma unroll
            for (int reg = 0; reg < 4; ++reg) {
                size_t idx = (size_t)(r0 + reg) * N + c;
                float val = acc[i][j][reg] + bj;
                if (EPI == EPI_RES) {
                    ((float*)out)[idx] = val + resid[idx];
                } else {
                    ((float*)out)[(size_t)blockIdx.z * M * N + idx] = val;
                }
            }
        }
    }
}

// ---------------- Flash attention v8: in-register P (permlane) + K/V dbuf ---
__global__ __launch_bounds__(256, 4) void attn_kernel(const bf16* __restrict__ QK,
                                                      const bf16* __restrict__ VT,
                                                      float* __restrict__ Op,
                                                      float* __restrict__ lp) {
    const int bx = blockIdx.x;
    const int h = bx >> 6, qb = (bx & 63) >> 1, kh = bx & 1;
    const int w = threadIdx.x >> 6, lane = threadIdx.x & 63;
    const int quad = lane >> 4, l16 = lane & 15;
    const int q0w = qb * 128 + w * 32;
    const bf16* Qh = QK + h * 64;
    const bf16* Kh = QK + 1024 + h * 64;
    const bf16* Vh = VT + (size_t)h * 64 * 4096;

    __shared__ char smem[32768];  // buf b at b*16384: Ks 8K | Vs 8K

    const int sw = l16 & 7;
    const int rloc = lane >> 3, slot = lane & 7;
    const int schunk = (slot ^ rloc) * 8;
    const int row0 = w * 16 + rloc, row1 = w * 16 + 8 + rloc;

    short8 qf[2][2];
#pragma unroll
    for (int qt = 0; qt < 2; ++qt)
#pragma unroll
        for (int c = 0; c < 2; ++c)
            qf[qt][c] = *(const short8*)(Qh + (size_t)(q0w + qt * 16 + l16) * 2048 + c * 32 + quad * 8);

    const short ob = (l16 == 0) ? (short)0x3F80 : (short)0;
    const short8 ones8 = {ob, ob, ob, ob, ob, ob, ob, ob};

    f32x4 acc[4][2] = {};
    f32x4 accl[2] = {};
    const f32x4 zero = {0.f, 0.f, 0.f, 0.f};
    const int ktBeg = kh * 2048;

    {
        bf16* Ksb = (bf16*)smem;
        bf16* Vsb = (bf16*)(smem + 8192);
        stage16(Kh + (size_t)(ktBeg + row0) * 2048 + schunk, Ksb + w * 1024);
        stage16(Kh + (size_t)(ktBeg + row1) * 2048 + schunk, Ksb + w * 1024 + 512);
        stage16(Vh + (size_t)row0 * 4096 + ktBeg + schunk, Vsb + w * 1024);
        stage16(Vh + (size_t)row1 * 4096 + ktBeg + schunk, Vsb + w * 1024 + 512);
    }

#pragma unroll 2
    for (int t = 0; t < 32; ++t) {
        char* curb = smem + (t & 1) * 16384;
        char* nxtb = smem + ((t + 1) & 1) * 16384;
        __builtin_amdgcn_s_barrier();
        if (t < 31) {
            const int ktA = ktBeg + (t + 1) * 64;
            bf16* Ksb = (bf16*)nxtb;
            bf16* Vsb = (bf16*)(nxtb + 8192);
            stage16(Kh + (size_t)(ktA + row0) * 2048 + schunk, Ksb + w * 1024);
            stage16(Kh + (size_t)(ktA + row1) * 2048 + schunk, Ksb + w * 1024 + 512);
            stage16(Vh + (size_t)row0 * 4096 + ktA + schunk, Vsb + w * 1024);
            stage16(Vh + (size_t)row1 * 4096 + ktA + schunk, Vsb + w * 1024 + 512);
            asm volatile("s_waitcnt vmcnt(4)" ::: "memory");
        } else {
            asm volatile("s_waitcnt vmcnt(0)" ::: "memory");
        }
        __builtin_amdgcn_s_barrier();

        const bf16* Ks = (const bf16*)curb;
        const bf16* Vs = (const bf16*)(curb + 8192);

        unsigned u[4][2][2];
#pragma unroll
        for (int nt = 0; nt < 4; ++nt) {
            const bf16* kr = Ks + (nt * 16 + l16) * 64;
            short8 k0 = *(const short8*)(kr + ((quad ^ sw) * 8));
            short8 k1 = *(const short8*)(kr + (((quad + 4) ^ sw) * 8));
#pragma unroll
            for (int qt = 0; qt < 2; ++qt) {
                f32x4 st = mfma16(k1, qf[qt][1], mfma16(k0, qf[qt][0], zero));
                u[nt][qt][0] = pkbf16(EXP2(st[0]), EXP2(st[1]));
                u[nt][qt][1] = pkbf16(EXP2(st[2]), EXP2(st[3]));
            }
        }
#pragma unroll
        for (int c = 0; c < 2; ++c) {
            short8 pB[2];
#pragma unroll
            for (int qt = 0; qt < 2; ++qt) {
                unsigned a0 = u[2 * c][qt][0], a1 = u[2 * c][qt][1];
                unsigned b0 = u[2 * c + 1][qt][0], b1 = u[2 * c + 1][qt][1];
                pl32swap(a0, b0);
                pl32swap(a1, b1);
                pl16swap(a0, b0);
                pl16swap(a1, b1);
                union { unsigned u4[4]; short8 s8; } pk;
                pk.u4[0] = a0; pk.u4[1] = a1; pk.u4[2] = b0; pk.u4[3] = b1;
                pB[qt] = pk.s8;
                accl[qt] = mfma16(ones8, pB[qt], accl[qt]);
            }
#pragma unroll
            for (int vt = 0; vt < 4; ++vt) {
                short8 vf = *(const short8*)(Vs + (vt * 16 + l16) * 64 + (((c * 4 + quad) ^ sw) * 8));
#pragma unroll
                for (int qt = 0; qt < 2; ++qt)
                    acc[vt][qt] = mfma16(vf, pB[qt], acc[vt][qt]);
            }
        }
    }
    float* Oz = Op + (size_t)kh * (4096 * 1024);
#pragma unroll
    for (int qt = 0; qt < 2; ++qt) {
        int q = q0w + qt * 16 + l16;
#pragma unroll
        for (int vt = 0; vt < 4; ++vt)
            *(f32x4*)(Oz + (size_t)q * 1024 + h * 64 + vt * 16 + quad * 4) = acc[vt][qt];
        if (quad == 0) lp[kh * 65536 + h * 4096 + q] = accl[qt][0];
    }
}

// ---------------- attn partial merge: o = (Op0+Op1)/(l0+l1), bf16 out -------
__global__ __launch_bounds__(256) void merge_attn(const float* __restrict__ Op,
                                                  const float* __restrict__ lp,
                                                  bf16* __restrict__ o) {
    int i = blockIdx.x * 256 + threadIdx.x;
    int d4 = i * 4;
    int s = d4 >> 10, d = d4 & 1023, h = d >> 6;
    f32x4 a = *(const f32x4*)(Op + d4);
    f32x4 b = *(const f32x4*)(Op + 4194304 + d4);
    float linv = 1.f / (lp[h * 4096 + s] + lp[65536 + h * 4096 + s]);
    s16x4 ov;
    ov[0] = tobs((a[0] + b[0]) * linv);
    ov[1] = tobs((a[1] + b[1]) * linv);
    ov[2] = tobs((a[2] + b[2]) * linv);
    ov[3] = tobs((a[3] + b[3]) * linv);
    *(s16x4*)(o + d4) = ov;
}

// ---------------- FFN2 split-K merge: out += pb0 + pb1 + b2 (in-place) ------
__global__ __launch_bounds__(256) void merge_ffn2(const float* __restrict__ pb,
                                                  const float* __restrict__ b2,
                                                  float* __restrict__ out) {
    int i = blockIdx.x * 256 + threadIdx.x;
    int d4 = i * 4, c = d4 & 1023;
    f32x4 a = *(const f32x4*)(pb + d4);
    f32x4 b = *(const f32x4*)(pb + 4194304 + d4);
    f32x4 r = *(const f32x4*)(out + d4);
    f32x4 bb = *(const f32x4*)(b2 + c);
    f32x4 v = {a[0] + b[0] + r[0] + bb[0], a[1] + b[1] + r[1] + bb[1],
               a[2] + b[2] + r[2] + bb[2], a[3] + b[3] + r[3] + bb[3]};
    *(f32x4*)(out + d4) = v;
}

extern "C" void kernel_launch(void* const* d_in, const int* in_sizes, int n_in,
                              void* d_out, int out_size, void* d_ws, size_t ws_size,
                              hipStream_t stream) {
    const float* x   = (const float*)d_in[0];
    const float* s1  = (const float*)d_in[1];
    const float* b1n = (const float*)d_in[2];
    const float* s2  = (const float*)d_in[3];
    const float* b2n = (const float*)d_in[4];
    const float* Wq  = (const float*)d_in[5];
    const float* bq  = (const float*)d_in[6];
    const float* Wk  = (const float*)d_in[7];
    const float* bk  = (const float*)d_in[8];
    const float* Wv  = (const float*)d_in[9];
    const float* bv  = (const float*)d_in[10];
    const float* Wo  = (const float*)d_in[11];
    const float* bo  = (const float*)d_in[12];
    const float* W1  = (const float*)d_in[13];
    const float* b1  = (const float*)d_in[14];
    const float* W2  = (const float*)d_in[15];
    const float* b2  = (const float*)d_in[16];

    char* ws = (char*)d_ws;                       // 96 MiB budget
    bf16*  y    = (bf16*)(ws);                    // 0-8: ln outs
    bf16*  QK   = (bf16*)(ws + (8ull  << 20));    // 8-24: roped q|k, stride 2048
    bf16*  BTo  = (bf16*)(ws + (24ull << 20));    // 24-26
    float* lp   = (float*)(ws + (26ull << 20));   // 26-26.5: attn l partials [2][H][S]
    float* bqkv = (float*)(ws + (27ull << 20));   // 27: 12KB
    bf16*  o    = (bf16*)(ws + (32ull << 20));    // 32-40: merged attn out
    bf16*  hb   = (bf16*)(ws + (40ull << 20));    // 40-72: FFN hidden
    bf16*  BTqkv= (bf16*)(ws + (40ull << 20));    // 40-46 (dead after QKV gemm)
    float* Op   = (float*)(ws + (40ull << 20));   // 40-72: attn O partials [2][S][D]
    bf16*  VT   = (bf16*)(ws + (72ull << 20));    // 72-80
    bf16*  BT1  = (bf16*)(ws + (80ull << 20));    // 80-88
    bf16*  BT2  = (bf16*)(ws + (88ull << 20));    // 88-96
    float* pb   = (float*)(ws);                   // 0-32: FFN2 split-K partials
    float* x1   = (float*)d_out;                  // fp32 residual lives in d_out

    wtrans_all<<<12300, 256, 0, stream>>>(Wq, Wk, Wv, Wo, W1, W2, bq, bk, bv,
                                          BTqkv, BTo, BT1, BT2, bqkv);

    ln_kernel<<<S, 256, 0, stream>>>(x, s1, b1n, y);

    // fused QKV GEMM (8-phase 256^2) with rope epilogue; q,k -> QK, V -> VT
    gemm256<EPI_QKV><<<dim3(12, 16), 512, 0, stream>>>(y, BTqkv, bqkv, QK, VT, 3072, D);

    attn_kernel<<<H * 64, 256, 0, stream>>>(QK, VT, Op, lp);
    merge_attn<<<4096, 256, 0, stream>>>(Op, lp, o);

    // O projection + residual (fp32) -> x1 (= d_out)
    gemm_bt<EPI_RES, 64><<<dim3(8, 64), 256, 0, stream>>>(o, BTo, bo, x, x1, nullptr, S, D, D, D);

    ln_kernel<<<S, 256, 0, stream>>>(x1, s2, b2n, y);

    // FFN1 + GELU (8-phase 256^2)
    gemm256<EPI_GELU><<<dim3(16, 16), 512, 0, stream>>>(y, BT1, b1, hb, nullptr, FF, D);

    // FFN2 split-K=2 -> fp32 partials, then merge with bias + residual
    gemm_bt<EPI_PART, 64><<<dim3(8, 64, 2), 256, 0, stream>>>(hb, BT2, b2, nullptr, pb, nullptr, S, D, FF, 2048);
    merge_ffn2<<<4096, 256, 0, stream>>>(pb, b2, x1);
}

// Round 5
// 409.503 us; speedup vs baseline: 1.1193x; 1.1193x over previous
//
#include <hip/hip_runtime.h>
#include <hip/hip_bf16.h>
#include <math.h>

using bf16 = __hip_bfloat16;
typedef __attribute__((ext_vector_type(8))) short short8;
typedef __attribute__((ext_vector_type(4))) short s16x4;
typedef __attribute__((ext_vector_type(4))) float f32x4;

constexpr int S = 4096, D = 1024, H = 16, HD = 64, FF = 4096;

static __device__ __forceinline__ float tof(bf16 v) { return __bfloat162float(v); }
static __device__ __forceinline__ bf16 tob(float v) { return __float2bfloat16(v); }
static __device__ __forceinline__ short tobs(float v) {
    bf16 h = __float2bfloat16(v);
    return *reinterpret_cast<short*>(&h);
}
static __device__ __forceinline__ unsigned pkbf16(float a, float b) {
    __hip_bfloat162 h = __float22bfloat162_rn(make_float2(a, b));
    return *reinterpret_cast<unsigned*>(&h);
}

#if __has_builtin(__builtin_amdgcn_exp2f)
#define EXP2(x) __builtin_amdgcn_exp2f(x)
#else
#define EXP2(x) exp2f(x)
#endif

static __device__ __forceinline__ f32x4 mfma16(short8 a, short8 b, f32x4 c) {
    return __builtin_amdgcn_mfma_f32_16x16x32_bf16(a, b, c, 0, 0, 0);
}
// async global->LDS, 16B per lane; LDS dest = wave-uniform base + lane*16
static __device__ __forceinline__ void stage16(const bf16* g, bf16* l) {
    __builtin_amdgcn_global_load_lds((__attribute__((address_space(1))) void*)g,
                                     (__attribute__((address_space(3))) void*)l, 16, 0, 0);
}
// cross-lane quad redistribution primitives (gfx950)
static __device__ __forceinline__ void pl32swap(unsigned& a, unsigned& b) {
    asm("v_permlane32_swap_b32 %0, %1" : "+v"(a), "+v"(b));
}
static __device__ __forceinline__ void pl16swap(unsigned& a, unsigned& b) {
    asm("v_permlane16_swap_b32 %0, %1" : "+v"(a), "+v"(b));
}

// ---------------- LayerNorm: fp32 in -> bf16 out ----------------------------
__global__ __launch_bounds__(256) void ln_kernel(const float* __restrict__ x,
                                                 const float* __restrict__ scale,
                                                 const float* __restrict__ bias,
                                                 bf16* __restrict__ y) {
    int row = blockIdx.x, t = threadIdx.x;
    const float* xr = x + (size_t)row * D;
    float v[4], s = 0.f, ss = 0.f;
#pragma unroll
    for (int i = 0; i < 4; ++i) {
        v[i] = xr[t + 256 * i];
        s += v[i]; ss += v[i] * v[i];
    }
    __shared__ float r0[256], r1[256];
    r0[t] = s; r1[t] = ss;
    __syncthreads();
    for (int off = 128; off; off >>= 1) {
        if (t < off) { r0[t] += r0[t + off]; r1[t] += r1[t + off]; }
        __syncthreads();
    }
    float mu  = r0[0] * (1.f / D);
    float var = r1[0] * (1.f / D) - mu * mu;
    float inv = rsqrtf(var + 1e-6f);
    bf16* yr = y + (size_t)row * D;
#pragma unroll
    for (int i = 0; i < 4; ++i) {
        int c = t + 256 * i;
        yr[c] = tob((v[i] - mu) * inv * scale[c] + bias[c]);
    }
}

// ------- all weight transposes (fp32 KxN -> bf16 NxK) + bias concat, fused --
__global__ __launch_bounds__(256) void wtrans_all(
    const float* __restrict__ Wq, const float* __restrict__ Wk,
    const float* __restrict__ Wv, const float* __restrict__ Wo,
    const float* __restrict__ W1, const float* __restrict__ W2,
    const float* __restrict__ bq, const float* __restrict__ bk,
    const float* __restrict__ bv,
    bf16* __restrict__ BTqkv, bf16* __restrict__ BTo,
    bf16* __restrict__ BT1, bf16* __restrict__ BT2, float* __restrict__ bqkv) {
    int id = blockIdx.x;
    if (id >= 12288) {
        int i = (id - 12288) * 256 + threadIdx.x;  // 3072
        bqkv[i] = i < 1024 ? bq[i] : (i < 2048 ? bk[i - 1024] : bv[i - 2048]);
        return;
    }
    const float* W; bf16* dst; int K, N, local;
    if (id < 3072)      { int s = id >> 10; W = s == 0 ? Wq : (s == 1 ? Wk : Wv);
                          dst = BTqkv + (size_t)s * 1048576; K = 1024; N = 1024; local = id & 1023; }
    else if (id < 4096) { W = Wo; dst = BTo; K = 1024; N = 1024; local = id - 3072; }
    else if (id < 8192) { W = W1; dst = BT1; K = 1024; N = 4096; local = id - 4096; }
    else                { W = W2; dst = BT2; K = 4096; N = 1024; local = id - 8192; }
    int ls = (N == 4096) ? 7 : 5;                  // log2(N/32)
    int nt = (local & ((1 << ls) - 1)) << 5, kt = (local >> ls) << 5;
    __shared__ float t[32][33];
    int tid = threadIdx.x, r = tid >> 5, c = tid & 31;
#pragma unroll
    for (int p = 0; p < 4; ++p)
        t[r + p * 8][c] = W[(size_t)(kt + r + p * 8) * N + nt + c];
    __syncthreads();
#pragma unroll
    for (int p = 0; p < 4; ++p)
        dst[(size_t)(nt + r + p * 8) * K + kt + c] = tob(t[c][r + p * 8]);
}

// ---------------- MFMA GEMM: C[M,N] = A[M,K] * BT[N,K]^T + bias -------------
// 2-phase double-buffered K-loop + T2 chunk XOR-swizzle (conflict-free,
// SQ_LDS_BANK_CONFLICT == 0 verified in round 3).
#define EPI_RES  1  // fp32 out = acc + bias + resid(fp32)   (out may alias resid)
#define EPI_GELU 2  // bf16 out = gelu(acc + bias)
#define EPI_QKV  3  // q/k: +bias, rope -> QK (stride 2048); v: -> VT transposed

template <int EPI, int MT>
__global__ __launch_bounds__(256, MT == 128 ? 2 : 3) void gemm_bt(
    const bf16* __restrict__ A, const bf16* __restrict__ BT,
    const float* __restrict__ bias, const float* resid, void* out, void* out2,
    int M, int N, int K, int kLen) {
    constexpr int NJ = (MT == 128) ? 4 : 2;
    __shared__ bf16 As[2][MT * 32];
    __shared__ bf16 Bs[2][128 * 32];
    const int tid = threadIdx.x;
    const int w = tid >> 6, lane = tid & 63;
    const int quad = lane >> 4, l16 = lane & 15;
    const int rowBase = blockIdx.y * MT, colBase = blockIdx.x * 128;
    const int kStart = blockIdx.z * kLen;
    const int wr = (MT == 128) ? (w >> 1) * 64 : 0;
    const int wc = (MT == 128) ? (w & 1) * 64 : w * 32;
    const int sr = lane >> 2;
    // staging source chunk, pre-swizzled: chunk ^= (row>>1)&3  (row = sr)
    const int skb = (((lane & 3) ^ ((lane >> 3) & 3)) * 8);
    // fragment-read chunk XOR key (row = l16 within each 16-row block)
    const int fr = (l16 >> 1) & 3;
    f32x4 acc[4][NJ] = {};

    auto stage = [&](int k0, int b) {
        if constexpr (MT == 128) {
#pragma unroll
            for (int t = 0; t < 2; ++t) {
                int inst = w * 2 + t;
                int r = inst * 16 + sr;
                stage16(A  + (size_t)(rowBase + r) * K + kStart + k0 + skb, &As[b][inst * 512]);
                stage16(BT + (size_t)(colBase + r) * K + kStart + k0 + skb, &Bs[b][inst * 512]);
            }
        } else {
            stage16(A + (size_t)(rowBase + w * 16 + sr) * K + kStart + k0 + skb, &As[b][w * 512]);
#pragma unroll
            for (int t = 0; t < 2; ++t) {
                int inst = w + t * 4;
                stage16(BT + (size_t)(colBase + inst * 16 + sr) * K + kStart + k0 + skb, &Bs[b][inst * 512]);
            }
        }
    };

    stage(0, 0);  // prologue: tile 0 -> buf 0
    const int nSteps = kLen >> 5;
    for (int s = 0; s < nSteps; ++s) {
        const int cb = s & 1;
        __builtin_amdgcn_s_barrier();  // all waves done reading buf cb^1 (iter s-1)
        if (s + 1 < nSteps) {
            stage((s + 1) << 5, cb ^ 1);
            // wait tile s landed; tile s+1's loads stay in flight
            if constexpr (MT == 128) asm volatile("s_waitcnt vmcnt(4)" ::: "memory");
            else                     asm volatile("s_waitcnt vmcnt(3)" ::: "memory");
        } else {
            asm volatile("s_waitcnt vmcnt(0)" ::: "memory");
        }
        __builtin_amdgcn_s_barrier();  // tile s visible to all waves
        const bf16* pa = &As[cb][(wr + l16) * 32 + (quad ^ fr) * 8];
        const bf16* pb = &Bs[cb][(wc + l16) * 32 + (quad ^ fr) * 8];
        short8 a[4], b[NJ];
#pragma unroll
        for (int i = 0; i < 4; ++i) a[i] = *(const short8*)(pa + i * 512);
#pragma unroll
        for (int j = 0; j < NJ; ++j) b[j] = *(const short8*)(pb + j * 512);
#pragma unroll
        for (int i = 0; i < 4; ++i)
#pragma unroll
            for (int j = 0; j < NJ; ++j) acc[i][j] = mfma16(a[i], b[j], acc[i][j]);
    }
    if (EPI == EPI_QKV) {
        bf16* QKo = (bf16*)out;   // (S, 2048) roped q|k
        bf16* VTo = (bf16*)out2;  // (H*64, S)
        if (colBase >= 2048) {  // V section: write transposed VT[c-2048][s]
#pragma unroll
            for (int j = 0; j < NJ; ++j) {
                int c = colBase + wc + j * 16 + l16;
                float bj = bias[c];
                size_t cc = (size_t)(c - 2048) * 4096;
#pragma unroll
                for (int i = 0; i < 4; ++i) {
                    int r0 = rowBase + wr + i * 16 + quad * 4;
                    s16x4 ov = {tobs(acc[i][j][0] + bj), tobs(acc[i][j][1] + bj),
                                tobs(acc[i][j][2] + bj), tobs(acc[i][j][3] + bj)};
                    *(s16x4*)(VTo + cc + r0) = ov;
                }
            }
        } else {  // Q or K section: bias + rope (pairs are (j, j+2) in-lane)
            const bool isq = colBase < 1024;
            const float qs = isq ? 0.125f * 1.44269504088896f : 1.f;
#pragma unroll
            for (int j2 = 0; j2 < 2; ++j2) {
                int dim = j2 * 16 + l16;
                float freq = __expf(-(float)dim * (9.210340371976184f / 32.f));
                int c1 = colBase + wc + j2 * 16 + l16, c2 = c1 + 32;
                float b1v = bias[c1], b2v = bias[c2];
#pragma unroll
                for (int i = 0; i < 4; ++i) {
#pragma unroll
                    for (int reg = 0; reg < 4; ++reg) {
                        int s = rowBase + wr + i * 16 + quad * 4 + reg;
                        float sn, cs;
                        sincosf((float)s * freq, &sn, &cs);
                        float x1 = acc[i][j2][reg] + b1v;
                        float x2 = acc[i][j2 + 2][reg] + b2v;
                        QKo[(size_t)s * 2048 + c1] = tob((x1 * cs - x2 * sn) * qs);
                        QKo[(size_t)s * 2048 + c2] = tob((x2 * cs + x1 * sn) * qs);
                    }
                }
            }
        }
    } else {
#pragma unroll
        for (int j = 0; j < NJ; ++j) {
            int c = colBase + wc + j * 16 + l16;
            float bj = bias[c];
#pragma unroll
            for (int i = 0; i < 4; ++i) {
                int r0 = rowBase + wr + i * 16 + quad * 4;
#pragma unroll
                for (int reg = 0; reg < 4; ++reg) {
                    size_t idx = (size_t)(r0 + reg) * N + c;
                    float val = acc[i][j][reg] + bj;
                    if (EPI == EPI_RES) {
                        ((float*)out)[idx] = val + resid[idx];
                    } else {
                        float g = 0.5f * val * (1.f + erff(val * 0.70710678118f));
                        ((bf16*)out)[idx] = tob(g);
                    }
                }
            }
        }
    }
}

// ---------------- Flash attention v9: full-row scan, fused normalize --------
// grid = H * (S/128) = 512; block = 4 waves, each 32 q-rows over ALL 4096 keys
// (64 tiles). In-register P (permlane), K/V double-buffer with counted
// vmcnt(4). l broadcast via __shfl from quad 0; bf16 output written directly
// (removes the kh-split fp32 partials + merge kernel entirely).
__global__ __launch_bounds__(256, 2) void attn_kernel(const bf16* __restrict__ QK,
                                                      const bf16* __restrict__ VT,
                                                      bf16* __restrict__ o) {
    const int bx = blockIdx.x;
    const int h = bx >> 5, qb = bx & 31;
    const int w = threadIdx.x >> 6, lane = threadIdx.x & 63;
    const int quad = lane >> 4, l16 = lane & 15;
    const int q0w = qb * 128 + w * 32;
    const bf16* Qh = QK + h * 64;
    const bf16* Kh = QK + 1024 + h * 64;
    const bf16* Vh = VT + (size_t)h * 64 * 4096;

    __shared__ char smem[32768];  // buf b at b*16384: Ks 8K | Vs 8K

    const int sw = l16 & 7;                       // frag XOR swizzle key (row&7)
    const int rloc = lane >> 3, slot = lane & 7;  // staging: 8 rows x 8 chunks
    const int schunk = (slot ^ rloc) * 8;
    const int row0 = w * 16 + rloc, row1 = w * 16 + 8 + rloc;

    // Q frags (loop-invariant): B-operand n=l16 (q), k=quad*8+j (hd)
    short8 qf[2][2];
#pragma unroll
    for (int qt = 0; qt < 2; ++qt)
#pragma unroll
        for (int c = 0; c < 2; ++c)
            qf[qt][c] = *(const short8*)(Qh + (size_t)(q0w + qt * 16 + l16) * 2048 + c * 32 + quad * 8);

    // ones A-fragment: row m=0 all-ones -> accl row 0 = sum_k P[k][q] = l
    const short ob = (l16 == 0) ? (short)0x3F80 : (short)0;
    const short8 ones8 = {ob, ob, ob, ob, ob, ob, ob, ob};

    f32x4 acc[4][2] = {};
    f32x4 accl[2] = {};
    const f32x4 zero = {0.f, 0.f, 0.f, 0.f};

    // prologue: stage tile 0 -> buf 0
    {
        bf16* Ksb = (bf16*)smem;
        bf16* Vsb = (bf16*)(smem + 8192);
        stage16(Kh + (size_t)row0 * 2048 + schunk, Ksb + w * 1024);
        stage16(Kh + (size_t)row1 * 2048 + schunk, Ksb + w * 1024 + 512);
        stage16(Vh + (size_t)row0 * 4096 + schunk, Vsb + w * 1024);
        stage16(Vh + (size_t)row1 * 4096 + schunk, Vsb + w * 1024 + 512);
    }

#pragma unroll 2
    for (int t = 0; t < 64; ++t) {
        char* curb = smem + (t & 1) * 16384;
        char* nxtb = smem + ((t + 1) & 1) * 16384;
        __builtin_amdgcn_s_barrier();  // all waves done reading nxtb (iter t-1)
        if (t < 63) {
            const int ktA = (t + 1) * 64;
            bf16* Ksb = (bf16*)nxtb;
            bf16* Vsb = (bf16*)(nxtb + 8192);
            stage16(Kh + (size_t)(ktA + row0) * 2048 + schunk, Ksb + w * 1024);
            stage16(Kh + (size_t)(ktA + row1) * 2048 + schunk, Ksb + w * 1024 + 512);
            stage16(Vh + (size_t)row0 * 4096 + ktA + schunk, Vsb + w * 1024);
            stage16(Vh + (size_t)row1 * 4096 + ktA + schunk, Vsb + w * 1024 + 512);
            asm volatile("s_waitcnt vmcnt(4)" ::: "memory");  // tile t landed, t+1 in flight
        } else {
            asm volatile("s_waitcnt vmcnt(0)" ::: "memory");
        }
        __builtin_amdgcn_s_barrier();  // tile t visible to all waves

        const bf16* Ks = (const bf16*)curb;
        const bf16* Vs = (const bf16*)(curb + 8192);

        // S^T = K*Q (A=K rows m=key, B=Q n=q), exp2 fused per nt; pack to bf16.
        unsigned u[4][2][2];
#pragma unroll
        for (int nt = 0; nt < 4; ++nt) {
            const bf16* kr = Ks + (nt * 16 + l16) * 64;
            short8 k0 = *(const short8*)(kr + ((quad ^ sw) * 8));
            short8 k1 = *(const short8*)(kr + (((quad + 4) ^ sw) * 8));
#pragma unroll
            for (int qt = 0; qt < 2; ++qt) {
                f32x4 st = mfma16(k1, qf[qt][1], mfma16(k0, qf[qt][0], zero));
                u[nt][qt][0] = pkbf16(EXP2(st[0]), EXP2(st[1]));
                u[nt][qt][1] = pkbf16(EXP2(st[2]), EXP2(st[3]));
            }
        }
        // Redistribute to PV B-fragment layout (k=c*32+quad*8+j) in-register.
#pragma unroll
        for (int c = 0; c < 2; ++c) {
            short8 pB[2];
#pragma unroll
            for (int qt = 0; qt < 2; ++qt) {
                unsigned a0 = u[2 * c][qt][0], a1 = u[2 * c][qt][1];
                unsigned b0 = u[2 * c + 1][qt][0], b1 = u[2 * c + 1][qt][1];
                pl32swap(a0, b0);
                pl32swap(a1, b1);
                pl16swap(a0, b0);
                pl16swap(a1, b1);
                union { unsigned u4[4]; short8 s8; } pk;
                pk.u4[0] = a0; pk.u4[1] = a1; pk.u4[2] = b0; pk.u4[3] = b1;
                pB[qt] = pk.s8;
                accl[qt] = mfma16(ones8, pB[qt], accl[qt]);
            }
            // PV: A = V^T (m=vdim), B = P^T (n=q, k=key)
#pragma unroll
            for (int vt = 0; vt < 4; ++vt) {
                short8 vf = *(const short8*)(Vs + (vt * 16 + l16) * 64 + (((c * 4 + quad) ^ sw) * 8));
#pragma unroll
                for (int qt = 0; qt < 2; ++qt)
                    acc[vt][qt] = mfma16(vf, pB[qt], acc[vt][qt]);
            }
        }
    }
    // epilogue: normalize by l (held at quad 0, lane q=l16) and write bf16
#pragma unroll
    for (int qt = 0; qt < 2; ++qt) {
        float lq = __shfl(accl[qt][0], l16, 64);  // broadcast from quad-0 lane
        float linv = 1.f / lq;
        int q = q0w + qt * 16 + l16;
#pragma unroll
        for (int vt = 0; vt < 4; ++vt) {
            s16x4 ov = {tobs(acc[vt][qt][0] * linv), tobs(acc[vt][qt][1] * linv),
                        tobs(acc[vt][qt][2] * linv), tobs(acc[vt][qt][3] * linv)};
            *(s16x4*)(o + (size_t)q * 1024 + h * 64 + vt * 16 + quad * 4) = ov;
        }
    }
}

extern "C" void kernel_launch(void* const* d_in, const int* in_sizes, int n_in,
                              void* d_out, int out_size, void* d_ws, size_t ws_size,
                              hipStream_t stream) {
    const float* x   = (const float*)d_in[0];
    const float* s1  = (const float*)d_in[1];
    const float* b1n = (const float*)d_in[2];
    const float* s2  = (const float*)d_in[3];
    const float* b2n = (const float*)d_in[4];
    const float* Wq  = (const float*)d_in[5];
    const float* bq  = (const float*)d_in[6];
    const float* Wk  = (const float*)d_in[7];
    const float* bk  = (const float*)d_in[8];
    const float* Wv  = (const float*)d_in[9];
    const float* bv  = (const float*)d_in[10];
    const float* Wo  = (const float*)d_in[11];
    const float* bo  = (const float*)d_in[12];
    const float* W1  = (const float*)d_in[13];
    const float* b1  = (const float*)d_in[14];
    const float* W2  = (const float*)d_in[15];
    const float* b2  = (const float*)d_in[16];

    char* ws = (char*)d_ws;                       // 96 MiB budget
    bf16*  y    = (bf16*)(ws);                    // 0-8: ln outs
    bf16*  QK   = (bf16*)(ws + (8ull  << 20));    // 8-24: roped q|k, stride 2048
    bf16*  BTo  = (bf16*)(ws + (24ull << 20));    // 24-26
    float* bqkv = (float*)(ws + (27ull << 20));   // 27: 12KB
    bf16*  o    = (bf16*)(ws + (32ull << 20));    // 32-40: attn out (bf16, direct)
    bf16*  hb   = (bf16*)(ws + (40ull << 20));    // 40-72: FFN hidden
    bf16*  BTqkv= (bf16*)(ws + (40ull << 20));    // 40-46 (dead after QKV gemm)
    bf16*  VT   = (bf16*)(ws + (72ull << 20));    // 72-80
    bf16*  BT1  = (bf16*)(ws + (80ull << 20));    // 80-88
    bf16*  BT2  = (bf16*)(ws + (88ull << 20));    // 88-96
    float* x1   = (float*)d_out;                  // fp32 residual lives in d_out

    wtrans_all<<<12300, 256, 0, stream>>>(Wq, Wk, Wv, Wo, W1, W2, bq, bk, bv,
                                          BTqkv, BTo, BT1, BT2, bqkv);

    ln_kernel<<<S, 256, 0, stream>>>(x, s1, b1n, y);

    // fused QKV GEMM with rope epilogue; q,k -> QK (stride 2048), V -> VT
    gemm_bt<EPI_QKV, 128><<<dim3(24, 32), 256, 0, stream>>>(y, BTqkv, bqkv, nullptr, QK, VT, S, 3072, D, D);

    // fused full-row attention (normalize + bf16 out, no merge pass)
    attn_kernel<<<H * 32, 256, 0, stream>>>(QK, VT, o);

    // O projection + residual (fp32) -> x1 (= d_out)
    gemm_bt<EPI_RES, 64><<<dim3(8, 64), 256, 0, stream>>>(o, BTo, bo, x, x1, nullptr, S, D, D, D);

    ln_kernel<<<S, 256, 0, stream>>>(x1, s2, b2n, y);

    // FFN1 + GELU
    gemm_bt<EPI_GELU, 128><<<dim3(32, 32), 256, 0, stream>>>(y, BT1, b1, nullptr, hb, nullptr, S, FF, D, D);

    // FFN2 (full K, no split) + bias + residual, in-place on x1
    gemm_bt<EPI_RES, 64><<<dim3(8, 64), 256, 0, stream>>>(hb, BT2, b2, x1, x1, nullptr, S, D, FF, FF);
}